// Round 6
// baseline (113.890 us; speedup 1.0000x reference)
//
#include <hip/hip_runtime.h>
#include <hip/hip_bf16.h>
#include <stdint.h>
#include <stddef.h>

// NT-Xent loss, B=4096, D=256, N=8192, T=0.5.
// normalize(+zero sumexp) -> fused ZZ^T GEMM + exp row-sum + positive capture
// -> 1-block finalize/mean. No NxN materialization.
//
// R6: R5 structure (K-loop eliminated, A register-resident full-D, B
// full-depth in LDS double-buffered, one barrier per j-tile) with TWO
// compiler-proof fixes:
//  (1) af loaded via VOLATILE loads: LLVM cannot rematerialize/duplicate a
//      volatile load, so af must stay in VGPRs (or visibly spill to scratch,
//      which FETCH/WRITE would expose). R4/R5: compiler remat'd af from L2
//      every t-iteration (VGPR_Count=120 < 128 needed) -> 8300 cyc/iter.
//  (2) #pragma unroll 1 on the t-loop: 16x unrolled body (~45 KB) blows the
//      32 KB I$.

#define B_ROWS 4096
#define D_DIM  256
#define N_ROWS 8192
#define BM 128
#define BN 64

typedef __bf16 bf16;
typedef bf16  bf16x8  __attribute__((ext_vector_type(8)));
typedef bf16  bf16x4  __attribute__((ext_vector_type(4)));
typedef float floatx4 __attribute__((ext_vector_type(4)));

// ---------------------------------------------------------------- normalize
// One wave per row: 256 fp32 -> L2-normalized bf16. Also zeroes sumexp[row].
__global__ __launch_bounds__(256) void normalize_kernel(
    const float* __restrict__ z_i, const float* __restrict__ z_j,
    bf16* __restrict__ zn, float* __restrict__ sumexp) {
  const int wave = threadIdx.x >> 6;
  const int lane = threadIdx.x & 63;
  const int row  = blockIdx.x * 4 + wave;
  const float* src = (row < B_ROWS) ? (z_i + (size_t)row * D_DIM)
                                    : (z_j + (size_t)(row - B_ROWS) * D_DIM);
  float4 v = ((const float4*)src)[lane];
  float ss = v.x * v.x + v.y * v.y + v.z * v.z + v.w * v.w;
  #pragma unroll
  for (int m = 1; m < 64; m <<= 1) ss += __shfl_xor(ss, m);
  const float rn = rsqrtf(ss);
  bf16x4 o;
  o[0] = (bf16)(v.x * rn);
  o[1] = (bf16)(v.y * rn);
  o[2] = (bf16)(v.z * rn);
  o[3] = (bf16)(v.w * rn);
  ((bf16x4*)(zn + (size_t)row * D_DIM))[lane] = o;
  if (lane == 0) sumexp[row] = 0.f;
}

// ------------------------------------------------------- fused sim+exp+sum
// Grid: 64 row-tiles x 8 col-chunks = 512 blocks (2/CU, exact residency).
// Block: rows [ri*128,+128), 16 j-tiles of 64 cols. 4 waves in 2x2; wave =
// 64 rows x 32 cols = 4x2 frags of 16x16x32 bf16 MFMA, full-D accumulate.
// LDS B layout XOR-swizzled (conflict-free, verified R2/R3): 16B chunk of
// row n, k-chunk kc lives at slot n*32 + ((kc&24) | ((kc&7)^(n&7))); swizzle
// applied on the GLOBAL source address (global_load_lds forces dest =
// base + lane*16). Read-side key: n&7 == lcol&7.
__global__ __launch_bounds__(256, 2) void simexp_kernel(
    const bf16* __restrict__ zn, float* __restrict__ sumexp,
    float* __restrict__ pos) {
  __shared__ __align__(16) bf16 Bs[2][BN * D_DIM];  // 2 x 32 KB

  const int tid   = threadIdx.x;
  const int wave  = tid >> 6;
  const int lane  = tid & 63;
  const int lcol  = lane & 15;   // MFMA: A row / B col / C col
  const int lquad = lane >> 4;   // MFMA: k-group / C row-group
  const int wr = (wave >> 1) * 64;  // wave row offset in 128
  const int wc = (wave & 1) * 32;   // wave col offset in 64
  const int ri = blockIdx.x >> 3;   // row tile 0..63
  const int cj = blockIdx.x & 7;    // col chunk 0..7
  const int row_base = ri * BM;
  const int jt0 = cj * 16;

  // stage B j-tile jt into buffer buf (8 global_load_lds x 16 B per thread)
  auto stageB = [&](int buf, int jt) {
    const bf16* src = zn + (size_t)jt * BN * D_DIM;
    #pragma unroll
    for (int it = 0; it < 8; ++it) {
      const int s   = it * 256 + tid;   // chunk slot 0..2047
      const int n   = s >> 5;           // row 0..63
      const int kcs = s & 31;           // swizzled k-chunk slot
      const int kc  = (kcs & 24) | ((kcs & 7) ^ (n & 7));
      __builtin_amdgcn_global_load_lds(
          (const __attribute__((address_space(1))) unsigned int*)
              (src + (size_t)n * D_DIM + kc * 8),
          (__attribute__((address_space(3))) unsigned int*)&Bs[buf][s * 8],
          16, 0, 0);
    }
  };

  stageB(0, jt0);  // first prefetch in flight while A loads below

  // A fragments, register-resident for the whole block (128 VGPRs).
  // af[ti][kq]: row = row_base+wr+ti*16+lcol, k = kq*32 + lquad*8 .. +7
  // VOLATILE loads: cannot be rematerialized or sunk into the loop by LLVM.
  floatx4 af[4][8];
  #pragma unroll
  for (int ti = 0; ti < 4; ++ti) {
    const bf16* arow =
        zn + (size_t)(row_base + wr + ti * 16 + lcol) * D_DIM + lquad * 8;
    #pragma unroll
    for (int kq = 0; kq < 8; ++kq)
      af[ti][kq] = *(volatile const floatx4*)(arow + kq * 32);
  }
  // Pin: opaque to the compiler (belt-and-suspenders with volatile).
  #pragma unroll
  for (int ti = 0; ti < 4; ++ti)
    #pragma unroll
    for (int kq = 0; kq < 8; ++kq)
      asm volatile("" : "+v"(af[ti][kq]));

  float rowsum[4][4];  // [ti][r]; row = wr + ti*16 + lquad*4 + r
  #pragma unroll
  for (int ti = 0; ti < 4; ++ti)
    #pragma unroll
    for (int r = 0; r < 4; ++r) rowsum[ti][r] = 0.f;

  #pragma unroll 1  // keep body ~3 KB; full unroll would blow the 32 KB I$
  for (int t = 0; t < 16; ++t) {
    const int jt = jt0 + t;
    __syncthreads();  // drains prefetch for buf[t&1]; fences buf[(t+1)&1] reads
    if (t < 15) stageB((t + 1) & 1, jt + 1);

    floatx4 acc[4][2];
    #pragma unroll
    for (int ti = 0; ti < 4; ++ti)
      #pragma unroll
      for (int tj = 0; tj < 2; ++tj) acc[ti][tj] = floatx4{0.f, 0.f, 0.f, 0.f};

    const bf16* bbase = &Bs[t & 1][0];
    #pragma unroll
    for (int kq = 0; kq < 8; ++kq) {
      const int kc  = kq * 4 + lquad;
      const int kcs = (kc & 24) | ((kc & 7) ^ (lcol & 7));
      bf16x8 bfr[2];
      #pragma unroll
      for (int tj = 0; tj < 2; ++tj) {
        const int n = wc + tj * 16 + lcol;
        bfr[tj] = *(const bf16x8*)(bbase + n * D_DIM + kcs * 8);
      }
      #pragma unroll
      for (int ti = 0; ti < 4; ++ti)
        #pragma unroll
        for (int tj = 0; tj < 2; ++tj)
          acc[ti][tj] = __builtin_amdgcn_mfma_f32_16x16x32_bf16(
              __builtin_bit_cast(bf16x8, af[ti][kq]), bfr[tj], acc[ti][tj],
              0, 0, 0);
    }

    // epilogue: e = exp(sim/T) = exp(2*dot) = 2^(v * 2/ln2)
    const int jth = jt >> 1;  // 128-granular col tile
    const bool special = (jth == ri) || (jth == ri + 32) || (jth + 32 == ri);
    const int col_base = jt * BN;
    #pragma unroll
    for (int ti = 0; ti < 4; ++ti) {
      #pragma unroll
      for (int tj = 0; tj < 2; ++tj) {
        #pragma unroll
        for (int r = 0; r < 4; ++r) {
          const float v = acc[ti][tj][r];
          float e = exp2f(v * 2.8853900817779268f);
          if (special) {
            const int rg = row_base + wr + ti * 16 + lquad * 4 + r;
            const int cg = col_base + wc + tj * 16 + lcol;
            if (cg == rg) e = 0.f;                       // mask self
            else if (cg == rg + B_ROWS || cg + B_ROWS == rg)
              pos[rg] = 2.0f * v;                        // positive sim
          }
          rowsum[ti][r] += e;
        }
      }
    }
  }

  // reduce the 16 col-lanes, then 1 atomic per row per wave
  #pragma unroll
  for (int ti = 0; ti < 4; ++ti) {
    #pragma unroll
    for (int r = 0; r < 4; ++r) {
      float s = rowsum[ti][r];
      s += __shfl_xor(s, 1);
      s += __shfl_xor(s, 2);
      s += __shfl_xor(s, 4);
      s += __shfl_xor(s, 8);
      if (lcol == 0) {
        const int grow = row_base + wr + ti * 16 + lquad * 4 + r;
        atomicAdd(&sumexp[grow], s);
      }
    }
  }
}

// ------------------------------------------------- finalize + mean (1 block)
// loss_i = log(sumexp_i) - pos_i ; out = mean(loss)
__global__ __launch_bounds__(1024) void reduce_kernel(
    const float* __restrict__ sumexp, const float* __restrict__ pos,
    float* __restrict__ out) {
  __shared__ float ws[16];
  const int tid = threadIdx.x;
  float s = 0.f;
  for (int k = tid; k < N_ROWS; k += 1024) s += __logf(sumexp[k]) - pos[k];
  #pragma unroll
  for (int m = 1; m < 64; m <<= 1) s += __shfl_xor(s, m);
  const int wave = tid >> 6, lane = tid & 63;
  if (lane == 0) ws[wave] = s;
  __syncthreads();
  if (wave == 0) {
    float t = (lane < 16) ? ws[lane] : 0.f;
    #pragma unroll
    for (int m = 1; m < 16; m <<= 1) t += __shfl_xor(t, m);
    if (lane == 0) out[0] = t * (1.0f / N_ROWS);
  }
}

extern "C" void kernel_launch(void* const* d_in, const int* in_sizes, int n_in,
                              void* d_out, int out_size, void* d_ws,
                              size_t ws_size, hipStream_t stream) {
  const float* z_i = (const float*)d_in[0];
  const float* z_j = (const float*)d_in[1];
  float* out = (float*)d_out;

  // workspace layout: zn (4 MB bf16) | sumexp (32 KB) | pos (32 KB)
  bf16* zn = (bf16*)d_ws;
  float* sumexp = (float*)((char*)d_ws + (size_t)N_ROWS * D_DIM * sizeof(bf16));
  float* pos = sumexp + N_ROWS;

  normalize_kernel<<<N_ROWS / 4, 256, 0, stream>>>(z_i, z_j, zn, sumexp);
  simexp_kernel<<<(N_ROWS / BM) * 8, 256, 0, stream>>>(zn, sumexp, pos);
  reduce_kernel<<<1, 1024, 0, stream>>>(sumexp, pos, out);
}

// Round 7
// 104.351 us; speedup vs baseline: 1.0914x; 1.0914x over previous
//
#include <hip/hip_runtime.h>
#include <hip/hip_bf16.h>
#include <stdint.h>
#include <stddef.h>

// NT-Xent loss, B=4096, D=256, N=8192, T=0.5.
// normalize(+zero sumexp) -> fused ZZ^T GEMM + exp row-sum + positive capture
// -> 1-block finalize/mean. No NxN materialization.
//
// R7: the epilogue exp was the wall all along. R1-R6 all had constant ~22 us
// of VALU busy-time regardless of GEMM structure: exp2f/__expf lower to an
// OCML call (~25 VALU insts = ~50 cyc/exp x 1024 exps/lane = 22 us busy).
// Fix: __builtin_amdgcn_exp2f -> single v_exp_f32 (1 ULP, threshold 0.18).
// Structure otherwise identical to R6 (A register/AGPR-resident full-D, B
// full-depth in LDS double-buffered, one barrier per j-tile, XOR-swizzled
// conflict-free staging).

#define B_ROWS 4096
#define D_DIM  256
#define N_ROWS 8192
#define BM 128
#define BN 64

typedef __bf16 bf16;
typedef bf16  bf16x8  __attribute__((ext_vector_type(8)));
typedef bf16  bf16x4  __attribute__((ext_vector_type(4)));
typedef float floatx4 __attribute__((ext_vector_type(4)));

// ---------------------------------------------------------------- normalize
// One wave per row: 256 fp32 -> L2-normalized bf16. Also zeroes sumexp[row].
__global__ __launch_bounds__(256) void normalize_kernel(
    const float* __restrict__ z_i, const float* __restrict__ z_j,
    bf16* __restrict__ zn, float* __restrict__ sumexp) {
  const int wave = threadIdx.x >> 6;
  const int lane = threadIdx.x & 63;
  const int row  = blockIdx.x * 4 + wave;
  const float* src = (row < B_ROWS) ? (z_i + (size_t)row * D_DIM)
                                    : (z_j + (size_t)(row - B_ROWS) * D_DIM);
  float4 v = ((const float4*)src)[lane];
  float ss = v.x * v.x + v.y * v.y + v.z * v.z + v.w * v.w;
  #pragma unroll
  for (int m = 1; m < 64; m <<= 1) ss += __shfl_xor(ss, m);
  const float rn = rsqrtf(ss);
  bf16x4 o;
  o[0] = (bf16)(v.x * rn);
  o[1] = (bf16)(v.y * rn);
  o[2] = (bf16)(v.z * rn);
  o[3] = (bf16)(v.w * rn);
  ((bf16x4*)(zn + (size_t)row * D_DIM))[lane] = o;
  if (lane == 0) sumexp[row] = 0.f;
}

// ------------------------------------------------------- fused sim+exp+sum
// Grid: 64 row-tiles x 8 col-chunks = 512 blocks (2/CU, exact residency).
// Block: rows [ri*128,+128), 16 j-tiles of 64 cols. 4 waves in 2x2; wave =
// 64 rows x 32 cols = 4x2 frags of 16x16x32 bf16 MFMA, full-D accumulate.
// LDS B layout XOR-swizzled (conflict-free, verified R2/R3): 16B chunk of
// row n, k-chunk kc lives at slot n*32 + ((kc&24) | ((kc&7)^(n&7))); swizzle
// applied on the GLOBAL source address (global_load_lds forces dest =
// base + lane*16). Read-side key: n&7 == lcol&7.
__global__ __launch_bounds__(256, 2) void simexp_kernel(
    const bf16* __restrict__ zn, float* __restrict__ sumexp,
    float* __restrict__ pos) {
  __shared__ __align__(16) bf16 Bs[2][BN * D_DIM];  // 2 x 32 KB

  const int tid   = threadIdx.x;
  const int wave  = tid >> 6;
  const int lane  = tid & 63;
  const int lcol  = lane & 15;   // MFMA: A row / B col / C col
  const int lquad = lane >> 4;   // MFMA: k-group / C row-group
  const int wr = (wave >> 1) * 64;  // wave row offset in 128
  const int wc = (wave & 1) * 32;   // wave col offset in 64
  const int ri = blockIdx.x >> 3;   // row tile 0..63
  const int cj = blockIdx.x & 7;    // col chunk 0..7
  const int row_base = ri * BM;
  const int jt0 = cj * 16;

  // stage B j-tile jt into buffer buf (8 global_load_lds x 16 B per thread)
  auto stageB = [&](int buf, int jt) {
    const bf16* src = zn + (size_t)jt * BN * D_DIM;
    #pragma unroll
    for (int it = 0; it < 8; ++it) {
      const int s   = it * 256 + tid;   // chunk slot 0..2047
      const int n   = s >> 5;           // row 0..63
      const int kcs = s & 31;           // swizzled k-chunk slot
      const int kc  = (kcs & 24) | ((kcs & 7) ^ (n & 7));
      __builtin_amdgcn_global_load_lds(
          (const __attribute__((address_space(1))) unsigned int*)
              (src + (size_t)n * D_DIM + kc * 8),
          (__attribute__((address_space(3))) unsigned int*)&Bs[buf][s * 8],
          16, 0, 0);
    }
  };

  stageB(0, jt0);  // first prefetch in flight while A loads below

  // A fragments, register-resident for the whole block.
  // af[ti][kq]: row = row_base+wr+ti*16+lcol, k = kq*32 + lquad*8 .. +7
  floatx4 af[4][8];
  #pragma unroll
  for (int ti = 0; ti < 4; ++ti) {
    const bf16* arow =
        zn + (size_t)(row_base + wr + ti * 16 + lcol) * D_DIM + lquad * 8;
    #pragma unroll
    for (int kq = 0; kq < 8; ++kq)
      af[ti][kq] = *(const floatx4*)(arow + kq * 32);
  }

  float rowsum[4][4];  // [ti][r]; row = wr + ti*16 + lquad*4 + r
  #pragma unroll
  for (int ti = 0; ti < 4; ++ti)
    #pragma unroll
    for (int r = 0; r < 4; ++r) rowsum[ti][r] = 0.f;

  #pragma unroll 1  // keep body small; full unroll would blow the 32 KB I$
  for (int t = 0; t < 16; ++t) {
    const int jt = jt0 + t;
    __syncthreads();  // drains prefetch for buf[t&1]; fences buf[(t+1)&1] reads
    if (t < 15) stageB((t + 1) & 1, jt + 1);

    floatx4 acc[4][2];
    #pragma unroll
    for (int ti = 0; ti < 4; ++ti)
      #pragma unroll
      for (int tj = 0; tj < 2; ++tj) acc[ti][tj] = floatx4{0.f, 0.f, 0.f, 0.f};

    const bf16* bbase = &Bs[t & 1][0];
    #pragma unroll
    for (int kq = 0; kq < 8; ++kq) {
      const int kc  = kq * 4 + lquad;
      const int kcs = (kc & 24) | ((kc & 7) ^ (lcol & 7));
      bf16x8 bfr[2];
      #pragma unroll
      for (int tj = 0; tj < 2; ++tj) {
        const int n = wc + tj * 16 + lcol;
        bfr[tj] = *(const bf16x8*)(bbase + n * D_DIM + kcs * 8);
      }
      #pragma unroll
      for (int ti = 0; ti < 4; ++ti)
        #pragma unroll
        for (int tj = 0; tj < 2; ++tj)
          acc[ti][tj] = __builtin_amdgcn_mfma_f32_16x16x32_bf16(
              __builtin_bit_cast(bf16x8, af[ti][kq]), bfr[tj], acc[ti][tj],
              0, 0, 0);
    }

    // epilogue: e = exp(sim/T) = exp(2*dot) = 2^(v * 2/ln2)
    // __builtin_amdgcn_exp2f = single v_exp_f32 (R1-R6 used exp2f/__expf ->
    // OCML call, ~22 us of VALU busy across the whole dispatch).
    const int jth = jt >> 1;  // 128-granular col tile
    const bool special = (jth == ri) || (jth == ri + 32) || (jth + 32 == ri);
    const int col_base = jt * BN;
    #pragma unroll
    for (int ti = 0; ti < 4; ++ti) {
      #pragma unroll
      for (int tj = 0; tj < 2; ++tj) {
        #pragma unroll
        for (int r = 0; r < 4; ++r) {
          const float v = acc[ti][tj][r];
          float e = __builtin_amdgcn_exp2f(v * 2.8853900817779268f);
          if (special) {
            const int rg = row_base + wr + ti * 16 + lquad * 4 + r;
            const int cg = col_base + wc + tj * 16 + lcol;
            if (cg == rg) e = 0.f;                       // mask self
            else if (cg == rg + B_ROWS || cg + B_ROWS == rg)
              pos[rg] = 2.0f * v;                        // positive sim
          }
          rowsum[ti][r] += e;
        }
      }
    }
  }

  // reduce the 16 col-lanes, then 1 atomic per row per wave
  #pragma unroll
  for (int ti = 0; ti < 4; ++ti) {
    #pragma unroll
    for (int r = 0; r < 4; ++r) {
      float s = rowsum[ti][r];
      s += __shfl_xor(s, 1);
      s += __shfl_xor(s, 2);
      s += __shfl_xor(s, 4);
      s += __shfl_xor(s, 8);
      if (lcol == 0) {
        const int grow = row_base + wr + ti * 16 + lquad * 4 + r;
        atomicAdd(&sumexp[grow], s);
      }
    }
  }
}

// ------------------------------------------------- finalize + mean (1 block)
// loss_i = log(sumexp_i) - pos_i ; out = mean(loss)
__global__ __launch_bounds__(1024) void reduce_kernel(
    const float* __restrict__ sumexp, const float* __restrict__ pos,
    float* __restrict__ out) {
  __shared__ float ws[16];
  const int tid = threadIdx.x;
  float s = 0.f;
  const float ln2 = 0.6931471805599453f;
  for (int k = tid; k < N_ROWS; k += 1024)
    s += __builtin_amdgcn_logf(sumexp[k]) * ln2 - pos[k];
  #pragma unroll
  for (int m = 1; m < 64; m <<= 1) s += __shfl_xor(s, m);
  const int wave = tid >> 6, lane = tid & 63;
  if (lane == 0) ws[wave] = s;
  __syncthreads();
  if (wave == 0) {
    float t = (lane < 16) ? ws[lane] : 0.f;
    #pragma unroll
    for (int m = 1; m < 16; m <<= 1) t += __shfl_xor(t, m);
    if (lane == 0) out[0] = t * (1.0f / N_ROWS);
  }
}

extern "C" void kernel_launch(void* const* d_in, const int* in_sizes, int n_in,
                              void* d_out, int out_size, void* d_ws,
                              size_t ws_size, hipStream_t stream) {
  const float* z_i = (const float*)d_in[0];
  const float* z_j = (const float*)d_in[1];
  float* out = (float*)d_out;

  // workspace layout: zn (4 MB bf16) | sumexp (32 KB) | pos (32 KB)
  bf16* zn = (bf16*)d_ws;
  float* sumexp = (float*)((char*)d_ws + (size_t)N_ROWS * D_DIM * sizeof(bf16));
  float* pos = sumexp + N_ROWS;

  normalize_kernel<<<N_ROWS / 4, 256, 0, stream>>>(z_i, z_j, zn, sumexp);
  simexp_kernel<<<(N_ROWS / BM) * 8, 256, 0, stream>>>(zn, sumexp, pos);
  reduce_kernel<<<1, 1024, 0, stream>>>(sumexp, pos, out);
}

// Round 8
// 100.287 us; speedup vs baseline: 1.1356x; 1.0405x over previous
//
#include <hip/hip_runtime.h>
#include <hip/hip_bf16.h>
#include <stdint.h>
#include <stddef.h>

// NT-Xent loss, B=4096, D=256, N=8192, T=0.5.
// normalize(+zero sumexp) -> fused symmetric ZZ^T GEMM + exp row/col-sum +
// positive capture -> 1-block finalize/mean. No NxN materialization.
//
// R8: SYMMETRY. sim is symmetric -> compute each 128x128 tile-pair {ri,ct}
// once; add row-sums of e=exp(2 sim) to rows(ri) and col-sums to rows(ct)
// (e_ij == e_ji bit-exactly: same bf16 inputs, same k-order). Coverage: for
// each ri, s = (ct-ri) mod 64 in {0..31}, plus s=32 for ri<32 only -> every
// unordered pair exactly once (2080 tiles vs 4096). s=0: mask self-diag,
// row-sums only. s=32: exactly the positive-pair tiles (pos[rg], pos[rg+B]).
// Halves MFMA, B-staging L2 traffic, LDS reads, and exp count at once
// (R7 was bound by all four at ~equal ~10-16 us shares).
// R7 carry-overs: __builtin_amdgcn_exp2f (single v_exp_f32; OCML call was
// ~22 us VALU), XOR-swizzled conflict-free LDS staging, A register-resident
// full-D, B full-depth LDS double-buffered, one barrier per j64-tile.

#define B_ROWS 4096
#define D_DIM  256
#define N_ROWS 8192
#define BM 128
#define BN 64

typedef __bf16 bf16;
typedef bf16  bf16x8  __attribute__((ext_vector_type(8)));
typedef bf16  bf16x4  __attribute__((ext_vector_type(4)));
typedef float floatx4 __attribute__((ext_vector_type(4)));

// ---------------------------------------------------------------- normalize
// One wave per row: 256 fp32 -> L2-normalized bf16. Also zeroes sumexp[row].
__global__ __launch_bounds__(256) void normalize_kernel(
    const float* __restrict__ z_i, const float* __restrict__ z_j,
    bf16* __restrict__ zn, float* __restrict__ sumexp) {
  const int wave = threadIdx.x >> 6;
  const int lane = threadIdx.x & 63;
  const int row  = blockIdx.x * 4 + wave;
  const float* src = (row < B_ROWS) ? (z_i + (size_t)row * D_DIM)
                                    : (z_j + (size_t)(row - B_ROWS) * D_DIM);
  float4 v = ((const float4*)src)[lane];
  float ss = v.x * v.x + v.y * v.y + v.z * v.z + v.w * v.w;
  #pragma unroll
  for (int m = 1; m < 64; m <<= 1) ss += __shfl_xor(ss, m);
  const float rn = rsqrtf(ss);
  bf16x4 o;
  o[0] = (bf16)(v.x * rn);
  o[1] = (bf16)(v.y * rn);
  o[2] = (bf16)(v.z * rn);
  o[3] = (bf16)(v.w * rn);
  ((bf16x4*)(zn + (size_t)row * D_DIM))[lane] = o;
  if (lane == 0) sumexp[row] = 0.f;
}

// ------------------------------------------------------- fused sim+exp+sum
// Grid: 64 ri x 8 cj = 512 blocks (2/CU). Block (ri,cj) handles tile-pairs
// s = 4cj+p, p=0..3 (+p=4 i.e. s=32 when cj==7 && ri<32); each pair = two
// 64-col sub-tiles -> 8 or 10 iterations. 4 waves in 2x2; wave = 64 rows x
// 32 cols = 4x2 frags of 16x16x32 bf16 MFMA, full-D accumulate.
// LDS B layout XOR-swizzled (conflict-free, verified R2/R3): 16B chunk of
// row n, k-chunk kc lives at slot n*32 + ((kc&24)|((kc&7)^(n&7))); swizzle
// applied on the GLOBAL source address. Read-side key: lcol&7.
__global__ __launch_bounds__(256, 2) void simexp_kernel(
    const bf16* __restrict__ zn, float* __restrict__ sumexp,
    float* __restrict__ pos) {
  __shared__ __align__(16) bf16 Bs[2][BN * D_DIM];  // 2 x 32 KB

  const int tid   = threadIdx.x;
  const int wave  = tid >> 6;
  const int lane  = tid & 63;
  const int lcol  = lane & 15;   // MFMA: A row / B col / C col
  const int lquad = lane >> 4;   // MFMA: k-group / C row-group
  const int wr = (wave >> 1) * 64;  // wave row offset in 128
  const int wc = (wave & 1) * 32;   // wave col offset in 64
  const int ri = blockIdx.x >> 3;   // row tile 0..63
  const int cj = blockIdx.x & 7;    // s-chunk 0..7
  const int row_base = ri * BM;
  const int niter = (cj == 7 && ri < 32) ? 10 : 8;

  // j64-tile index for iteration it: pair p = it>>1, ct = (ri+4cj+p) & 63
  auto jt64 = [&](int it) {
    return 2 * ((ri + 4 * cj + (it >> 1)) & 63) + (it & 1);
  };

  // stage B j64-tile jt into buffer buf (8 global_load_lds x 16 B / thread)
  auto stageB = [&](int buf, int jt) {
    const bf16* src = zn + (size_t)jt * BN * D_DIM;
    #pragma unroll
    for (int it = 0; it < 8; ++it) {
      const int s   = it * 256 + tid;   // chunk slot 0..2047
      const int n   = s >> 5;           // row 0..63
      const int kcs = s & 31;           // swizzled k-chunk slot
      const int kc  = (kcs & 24) | ((kcs & 7) ^ (n & 7));
      __builtin_amdgcn_global_load_lds(
          (const __attribute__((address_space(1))) unsigned int*)
              (src + (size_t)n * D_DIM + kc * 8),
          (__attribute__((address_space(3))) unsigned int*)&Bs[buf][s * 8],
          16, 0, 0);
    }
  };

  stageB(0, jt64(0));  // first prefetch in flight while A loads below

  // A fragments, register-resident for the whole block.
  // af[ti][kq]: row = row_base+wr+ti*16+lcol, k = kq*32 + lquad*8 .. +7
  floatx4 af[4][8];
  #pragma unroll
  for (int ti = 0; ti < 4; ++ti) {
    const bf16* arow =
        zn + (size_t)(row_base + wr + ti * 16 + lcol) * D_DIM + lquad * 8;
    #pragma unroll
    for (int kq = 0; kq < 8; ++kq)
      af[ti][kq] = *(const floatx4*)(arow + kq * 32);
  }

  float rowsum[4][4];  // [ti][r]; row = wr + ti*16 + lquad*4 + r
  #pragma unroll
  for (int ti = 0; ti < 4; ++ti)
    #pragma unroll
    for (int r = 0; r < 4; ++r) rowsum[ti][r] = 0.f;

  #pragma unroll 1  // keep body small (I$); niter is dynamic anyway
  for (int t = 0; t < niter; ++t) {
    __syncthreads();  // drains prefetch for buf[t&1]; fences other-buf reads
    if (t + 1 < niter) stageB((t + 1) & 1, jt64(t + 1));

    floatx4 acc[4][2];
    #pragma unroll
    for (int ti = 0; ti < 4; ++ti)
      #pragma unroll
      for (int tj = 0; tj < 2; ++tj) acc[ti][tj] = floatx4{0.f, 0.f, 0.f, 0.f};

    const bf16* bbase = &Bs[t & 1][0];
    #pragma unroll
    for (int kq = 0; kq < 8; ++kq) {
      const int kc  = kq * 4 + lquad;
      const int kcs = (kc & 24) | ((kc & 7) ^ (lcol & 7));
      bf16x8 bfr[2];
      #pragma unroll
      for (int tj = 0; tj < 2; ++tj) {
        const int n = wc + tj * 16 + lcol;
        bfr[tj] = *(const bf16x8*)(bbase + n * D_DIM + kcs * 8);
      }
      #pragma unroll
      for (int ti = 0; ti < 4; ++ti)
        #pragma unroll
        for (int tj = 0; tj < 2; ++tj)
          acc[ti][tj] = __builtin_amdgcn_mfma_f32_16x16x32_bf16(
              __builtin_bit_cast(bf16x8, af[ti][kq]), bfr[tj], acc[ti][tj],
              0, 0, 0);
    }

    // epilogue: e = exp(sim/T) = exp(2*dot) = 2^(v * 2/ln2)
    const int s    = 4 * cj + (t >> 1);
    const bool diag = (s == 0);
    const bool posT = (s == 32);
    const int jt = jt64(t);
    const int col_base = jt * BN;
    float colsum[2] = {0.f, 0.f};
    #pragma unroll
    for (int ti = 0; ti < 4; ++ti) {
      #pragma unroll
      for (int tj = 0; tj < 2; ++tj) {
        #pragma unroll
        for (int r = 0; r < 4; ++r) {
          const float v = acc[ti][tj][r];
          float e = __builtin_amdgcn_exp2f(v * 2.8853900817779268f);
          if (diag || posT) {
            const int rg = row_base + wr + ti * 16 + lquad * 4 + r;
            const int cg = col_base + wc + tj * 16 + lcol;
            if (diag && cg == rg) e = 0.f;               // mask self
            if (posT && cg == rg + B_ROWS) {             // positive pair
              pos[rg] = 2.0f * v;
              pos[cg] = 2.0f * v;
            }
          }
          rowsum[ti][r] += e;
          colsum[tj]    += e;
        }
      }
    }

    // symmetric contribution: col-sums -> rows of the partner tile.
    // (skip on diag tile: both orientations already inside the tile)
    if (!diag) {
      #pragma unroll
      for (int tj = 0; tj < 2; ++tj) {
        float cs = colsum[tj];
        cs += __shfl_xor(cs, 16);
        cs += __shfl_xor(cs, 32);
        if (lquad == 0)
          atomicAdd(&sumexp[col_base + wc + tj * 16 + lcol], cs);
      }
    }
  }

  // reduce the 16 col-lanes of rowsum, then 1 atomic per row per wave
  #pragma unroll
  for (int ti = 0; ti < 4; ++ti) {
    #pragma unroll
    for (int r = 0; r < 4; ++r) {
      float s2 = rowsum[ti][r];
      s2 += __shfl_xor(s2, 1);
      s2 += __shfl_xor(s2, 2);
      s2 += __shfl_xor(s2, 4);
      s2 += __shfl_xor(s2, 8);
      if (lcol == 0) {
        const int grow = row_base + wr + ti * 16 + lquad * 4 + r;
        atomicAdd(&sumexp[grow], s2);
      }
    }
  }
}

// ------------------------------------------------- finalize + mean (1 block)
// loss_i = log(sumexp_i) - pos_i ; out = mean(loss)
__global__ __launch_bounds__(1024) void reduce_kernel(
    const float* __restrict__ sumexp, const float* __restrict__ pos,
    float* __restrict__ out) {
  __shared__ float ws[16];
  const int tid = threadIdx.x;
  float s = 0.f;
  const float ln2 = 0.6931471805599453f;
  for (int k = tid; k < N_ROWS; k += 1024)
    s += __builtin_amdgcn_logf(sumexp[k]) * ln2 - pos[k];
  #pragma unroll
  for (int m = 1; m < 64; m <<= 1) s += __shfl_xor(s, m);
  const int wave = tid >> 6, lane = tid & 63;
  if (lane == 0) ws[wave] = s;
  __syncthreads();
  if (wave == 0) {
    float t = (lane < 16) ? ws[lane] : 0.f;
    #pragma unroll
    for (int m = 1; m < 16; m <<= 1) t += __shfl_xor(t, m);
    if (lane == 0) out[0] = t * (1.0f / N_ROWS);
  }
}

extern "C" void kernel_launch(void* const* d_in, const int* in_sizes, int n_in,
                              void* d_out, int out_size, void* d_ws,
                              size_t ws_size, hipStream_t stream) {
  const float* z_i = (const float*)d_in[0];
  const float* z_j = (const float*)d_in[1];
  float* out = (float*)d_out;

  // workspace layout: zn (4 MB bf16) | sumexp (32 KB) | pos (32 KB)
  bf16* zn = (bf16*)d_ws;
  float* sumexp = (float*)((char*)d_ws + (size_t)N_ROWS * D_DIM * sizeof(bf16));
  float* pos = sumexp + N_ROWS;

  normalize_kernel<<<N_ROWS / 4, 256, 0, stream>>>(z_i, z_j, zn, sumexp);
  simexp_kernel<<<512, 256, 0, stream>>>(zn, sumexp, pos);
  reduce_kernel<<<1, 1024, 0, stream>>>(sumexp, pos, out);
}